// Round 4
// baseline (207.957 us; speedup 1.0000x reference)
//
#include <hip/hip_runtime.h>
#include <math.h>

#define S_ 3
#define G_ 8
#define B_ 2048
#define C_ 512
#define P_ 64
#define N_ (S_ * G_ * B_)   // 49152

typedef __attribute__((ext_vector_type(8))) short short8;
typedef __attribute__((ext_vector_type(4))) float f32x4;
typedef __attribute__((ext_vector_type(4))) unsigned int uint4v;
typedef __attribute__((ext_vector_type(2))) unsigned int uint2v;

__device__ __forceinline__ unsigned f2bf1(float f) {
    union { float f; unsigned u; } c; c.f = f;
    unsigned u = c.u;
    u += 0x7fffu + ((u >> 16) & 1u);   // RNE
    return u >> 16;
}
__device__ __forceinline__ unsigned pk2(float a, float b) {
    return f2bf1(a) | (f2bf1(b) << 16);
}

// ---------------------------------------------------------------------------
// Kernel 0: zero the outputs accumulator region
// ---------------------------------------------------------------------------
__global__ void zero_kernel(float* __restrict__ out) {
    int i = blockIdx.x * blockDim.x + threadIdx.x;   // 65536 float4 slots
    ((f32x4*)out)[i] = (f32x4){0.f, 0.f, 0.f, 0.f};
}

// ---------------------------------------------------------------------------
// Kernel 1: prep — w -> bf16 row-major, csq[p], rbeta[p] = 1/sigmoid(sf)
// ---------------------------------------------------------------------------
__global__ __launch_bounds__(64) void prep_kernel(
    const float* __restrict__ w, const float* __restrict__ sf,
    unsigned short* __restrict__ wb, float* __restrict__ csq,
    float* __restrict__ rbeta)
{
    const int p = blockIdx.x, l = threadIdx.x;
    const float* wr = w + (size_t)p * C_ + l * 8;
    f32x4 a = *(const f32x4*)wr;
    f32x4 b = *(const f32x4*)(wr + 4);
    float s = a[0]*a[0] + a[1]*a[1] + a[2]*a[2] + a[3]*a[3]
            + b[0]*b[0] + b[1]*b[1] + b[2]*b[2] + b[3]*b[3];
    uint4v pk;
    pk.x = pk2(a[0], a[1]); pk.y = pk2(a[2], a[3]);
    pk.z = pk2(b[0], b[1]); pk.w = pk2(b[2], b[3]);
    *(uint4v*)&wb[(size_t)p * C_ + l * 8] = pk;
#pragma unroll
    for (int off = 1; off < 64; off <<= 1) s += __shfl_xor(s, off, 64);
    if (l == 0) csq[p] = s;
    if (p == 0) rbeta[l] = 1.0f + expf(-sf[l]);
}

// ---------------------------------------------------------------------------
// Kernel 2: assign GEMM. 384 blocks x 256 thr. Tile 128 rows x 64 p, BK=64.
// x staged fp32 (stride 68: conflict-free b128), w staged bf16 (stride 72).
// fp32->bf16 at frag read; |x|^2 fused; softmax by shuffle; epilogue also
// emits transposed bf16 a_t via LDS transpose (reusing the x-tile memory).
// ---------------------------------------------------------------------------
#define XS_STR 68
#define WS_STR 72
__global__ __launch_bounds__(256, 3) void assign_gemm(
    const float* __restrict__ x, const unsigned short* __restrict__ wb,
    const float* __restrict__ csq, const float* __restrict__ rbeta,
    float* __restrict__ assign, unsigned short* __restrict__ a_t)
{
    __shared__ __align__(16) char smem[128 * XS_STR * 4 + 64 * WS_STR * 2];
    float* xs = (float*)smem;                                   // [128][68] fp32
    unsigned short* wsh = (unsigned short*)(smem + 128 * XS_STR * 4); // [64][72] bf16
    float* lg = (float*)smem;                                   // epilogue alias [128][68]

    const int t    = threadIdx.x;
    const int lane = t & 63;
    const int wv   = t >> 6;
    const int q    = lane >> 4;
    const int col  = lane & 15;
    const int n0   = blockIdx.x * 128;

    float csqv[4], rbv[4];
#pragma unroll
    for (int nt = 0; nt < 4; ++nt) {
        csqv[nt] = csq[16 * nt + col];
        rbv[nt]  = rbeta[16 * nt + col];
    }

    f32x4 acc[2][4];
#pragma unroll
    for (int mt = 0; mt < 2; ++mt)
#pragma unroll
        for (int nt = 0; nt < 4; ++nt) acc[mt][nt] = (f32x4){0.f, 0.f, 0.f, 0.f};
    float xsq[2] = {0.f, 0.f};

    const int srow = lane >> 4;     // 0..3
    const int sseg = lane & 15;     // 16B segment
    const int wp   = lane >> 3;     // 0..7
    const int wseg = lane & 7;

    for (int ch = 0; ch < 8; ++ch) {
        const int k0 = ch * 64;
        // ---- stage x-tile: 128 rows x 64 k fp32, coalesced 4KB/instr ----
#pragma unroll
        for (int i = 0; i < 8; ++i) {
            const int row = wv * 32 + i * 4 + srow;
            f32x4 v = *(const f32x4*)(x + (size_t)(n0 + row) * C_ + k0 + sseg * 4);
            *(f32x4*)&xs[row * XS_STR + sseg * 4] = v;
        }
        // ---- stage w-tile: 64 p x 64 k bf16 ----
#pragma unroll
        for (int i = 0; i < 2; ++i) {
            const int p = wv * 16 + i * 8 + wp;
            uint4v wv4 = *(const uint4v*)&wb[(size_t)p * C_ + k0 + wseg * 8];
            *(uint4v*)&wsh[p * WS_STR + wseg * 8] = wv4;
        }
        __syncthreads();

#pragma unroll
        for (int s = 0; s < 2; ++s) {
            const int koff = s * 32 + q * 8;
            short8 bf[4];
#pragma unroll
            for (int nt = 0; nt < 4; ++nt)
                bf[nt] = *(const short8*)&wsh[(16 * nt + col) * WS_STR + koff];
#pragma unroll
            for (int mt = 0; mt < 2; ++mt) {
                const int row = wv * 32 + 16 * mt + col;
                f32x4 f0 = *(const f32x4*)&xs[row * XS_STR + koff];
                f32x4 f1 = *(const f32x4*)&xs[row * XS_STR + koff + 4];
                xsq[mt] += f0.x*f0.x + f0.y*f0.y + f0.z*f0.z + f0.w*f0.w
                         + f1.x*f1.x + f1.y*f1.y + f1.z*f1.z + f1.w*f1.w;
                union { uint4v u; short8 s8; } cv;
                cv.u.x = pk2(f0.x, f0.y); cv.u.y = pk2(f0.z, f0.w);
                cv.u.z = pk2(f1.x, f1.y); cv.u.w = pk2(f1.z, f1.w);
#pragma unroll
                for (int nt = 0; nt < 4; ++nt)
                    acc[mt][nt] = __builtin_amdgcn_mfma_f32_16x16x32_bf16(
                        cv.s8, bf[nt], acc[mt][nt], 0, 0, 0);
            }
        }
        __syncthreads();
    }

    // full |x|^2 per row (lane's quarter -> full via q-reduction)
#pragma unroll
    for (int mt = 0; mt < 2; ++mt) {
        xsq[mt] += __shfl_xor(xsq[mt], 16, 64);
        xsq[mt] += __shfl_xor(xsq[mt], 32, 64);
    }
    float xsqr[2][4];
#pragma unroll
    for (int mt = 0; mt < 2; ++mt)
#pragma unroll
        for (int reg = 0; reg < 4; ++reg)
            xsqr[mt][reg] = __shfl(xsq[mt], 4 * q + reg, 64);

    // ---- logits + softmax + store (assign fp32 + lg scratch) ----
#pragma unroll
    for (int mt = 0; mt < 2; ++mt) {
#pragma unroll
        for (int reg = 0; reg < 4; ++reg) {
            const int row = wv * 32 + 16 * mt + 4 * q + reg;
            float vv[4], vmax = -3.4e38f;
#pragma unroll
            for (int nt = 0; nt < 4; ++nt) {
                float v = 2.0f * acc[mt][nt][reg] - xsqr[mt][reg] - csqv[nt];
                v = fminf(v, 0.0f) * rbv[nt];
                vv[nt] = v;
                vmax = fmaxf(vmax, v);
            }
#pragma unroll
            for (int off = 1; off < 16; off <<= 1)
                vmax = fmaxf(vmax, __shfl_xor(vmax, off, 64));
            float e[4], ss = 0.f;
#pragma unroll
            for (int nt = 0; nt < 4; ++nt) { e[nt] = __expf(vv[nt] - vmax); ss += e[nt]; }
#pragma unroll
            for (int off = 1; off < 16; off <<= 1)
                ss += __shfl_xor(ss, off, 64);
            const float inv = 1.0f / ss;
#pragma unroll
            for (int nt = 0; nt < 4; ++nt) {
                const float val = e[nt] * inv;
                assign[(size_t)(n0 + row) * P_ + 16 * nt + col] = val;
                lg[row * XS_STR + 16 * nt + col] = val;
            }
        }
    }
    __syncthreads();

    // ---- transposed bf16 a_t[p][n]: thread = (p = t&63, nseg = wv*32) ----
    const int p    = t & 63;
    const int nbas = wv * 32;
    float v[32];
#pragma unroll
    for (int i = 0; i < 32; ++i) v[i] = lg[(nbas + i) * XS_STR + p];
    uint4v d0, d1;
    d0.x = pk2(v[0], v[1]);   d0.y = pk2(v[2], v[3]);
    d0.z = pk2(v[4], v[5]);   d0.w = pk2(v[6], v[7]);
    d1.x = pk2(v[8], v[9]);   d1.y = pk2(v[10], v[11]);
    d1.z = pk2(v[12], v[13]); d1.w = pk2(v[14], v[15]);
    unsigned short* dst = a_t + (size_t)p * N_ + n0 + nbas;
    *(uint4v*)dst = d0;
    *(uint4v*)(dst + 8) = d1;
    d0.x = pk2(v[16], v[17]); d0.y = pk2(v[18], v[19]);
    d0.z = pk2(v[20], v[21]); d0.w = pk2(v[22], v[23]);
    d1.x = pk2(v[24], v[25]); d1.y = pk2(v[26], v[27]);
    d1.z = pk2(v[28], v[29]); d1.w = pk2(v[30], v[31]);
    *(uint4v*)(dst + 16) = d0;
    *(uint4v*)(dst + 24) = d1;
}

// ---------------------------------------------------------------------------
// Kernel 3: group GEMM out[g,p,c] += sum_n a[n,p] x[n,c].
// Grid (8 g, 8 c-tiles of 64, 12 k-splits of 512). Tile 64p x 64c, BK=64.
// a_t staged coalesced [p][n] bf16 (stride 72, conflict-free b128 frags);
// x-tile register-transposed into [c][n] bf16 (stride 72). atomicAdd merge.
// ---------------------------------------------------------------------------
__global__ __launch_bounds__(256, 3) void group_gemm(
    const float* __restrict__ x, const unsigned short* __restrict__ a_t,
    float* __restrict__ out)
{
    __shared__ __align__(16) unsigned short ash[64 * WS_STR];  // [p][n]
    __shared__ __align__(16) unsigned short xts[64 * WS_STR];  // [c][n]

    const int t    = threadIdx.x;
    const int lane = t & 63;
    const int wv   = t >> 6;
    const int q    = lane >> 4;
    const int col  = lane & 15;
    const int g    = blockIdx.x;
    const int c0   = blockIdx.y * 64;
    const int ks   = blockIdx.z;         // 0..11
    const int sc   = ks >> 2;
    const int b0   = (ks & 3) * 512;
    const size_t base = (size_t)sc * (G_ * B_) + (size_t)g * B_ + b0;

    f32x4 acc[4];
#pragma unroll
    for (int mt = 0; mt < 4; ++mt) acc[mt] = (f32x4){0.f, 0.f, 0.f, 0.f};

    const int ap   = t >> 3;            // staging p (0..31 per half)
    const int aseg = t & 7;
    const int r0   = (t >> 4) * 4;      // transpose rows (0..60)
    const int scol = t & 15;

    for (int ch = 0; ch < 8; ++ch) {
        const int nb = ch * 64;
        // ---- stage a-tile: 64p x 64n bf16, coalesced ----
#pragma unroll
        for (int i = 0; i < 2; ++i) {
            const int p = i * 32 + ap;
            uint4v av = *(const uint4v*)&a_t[(size_t)p * N_ + base + nb + aseg * 8];
            *(uint4v*)&ash[p * WS_STR + aseg * 8] = av;
        }
        // ---- stage x-tile transposed: 64n x 64c -> [c][n] bf16 ----
        const size_t rb = (base + nb + r0) * C_ + c0 + scol * 4;
        f32x4 m0 = *(const f32x4*)(x + rb);
        f32x4 m1 = *(const f32x4*)(x + rb + C_);
        f32x4 m2 = *(const f32x4*)(x + rb + 2 * C_);
        f32x4 m3 = *(const f32x4*)(x + rb + 3 * C_);
#pragma unroll
        for (int cc = 0; cc < 4; ++cc) {
            const int c = scol * 4 + cc;
            uint2v u;
            u.x = pk2(m0[cc], m1[cc]);
            u.y = pk2(m2[cc], m3[cc]);
            *(uint2v*)&xts[c * WS_STR + r0] = u;
        }
        __syncthreads();

#pragma unroll
        for (int s = 0; s < 2; ++s) {
            const int koff = s * 32 + q * 8;
            short8 bfr = *(const short8*)&xts[(wv * 16 + col) * WS_STR + koff];
#pragma unroll
            for (int mt = 0; mt < 4; ++mt) {
                short8 afr = *(const short8*)&ash[(16 * mt + col) * WS_STR + koff];
                acc[mt] = __builtin_amdgcn_mfma_f32_16x16x32_bf16(afr, bfr, acc[mt], 0, 0, 0);
            }
        }
        __syncthreads();
    }

    // ---- epilogue: p = 16*mt + 4q + reg, c = c0 + wv*16 + col ----
#pragma unroll
    for (int mt = 0; mt < 4; ++mt) {
#pragma unroll
        for (int reg = 0; reg < 4; ++reg) {
            const int p = 16 * mt + 4 * q + reg;
            const int c = c0 + wv * 16 + col;
            atomicAdd(&out[(size_t)g * (P_ * C_) + (size_t)p * C_ + c], acc[mt][reg]);
        }
    }
}

// ---------------------------------------------------------------------------
extern "C" void kernel_launch(void* const* d_in, const int* in_sizes, int n_in,
                              void* d_out, int out_size, void* d_ws, size_t ws_size,
                              hipStream_t stream) {
    const float* x  = (const float*)d_in[0];   // node_feats [3, 16384, 512]
    const float* w  = (const float*)d_in[1];   // weight [64, 512]
    const float* sf = (const float*)d_in[2];   // smooth_factor [64]

    float* out    = (float*)d_out;              // outputs [8, 64, 512]
    float* assign = out + (size_t)G_ * P_ * C_; // assign [N, 64] fp32

    unsigned short* wb    = (unsigned short*)d_ws;                  // 65536 B
    float*          csq   = (float*)((char*)d_ws + 65536);          // 256 B
    float*          rbeta = (float*)((char*)d_ws + 65792);          // 256 B
    unsigned short* a_t   = (unsigned short*)((char*)d_ws + 66048); // 6.3 MB

    zero_kernel<<<(G_ * P_ * C_) / (4 * 256), 256, 0, stream>>>(out);
    prep_kernel<<<P_, 64, 0, stream>>>(w, sf, wb, csq, rbeta);
    assign_gemm<<<N_ / 128, 256, 0, stream>>>(x, wb, csq, rbeta, assign, a_t);
    dim3 gridB(G_, C_ / 64, 12);
    group_gemm<<<gridB, 256, 0, stream>>>(x, a_t, out);
}

// Round 5
// 188.710 us; speedup vs baseline: 1.1020x; 1.1020x over previous
//
#include <hip/hip_runtime.h>
#include <math.h>

#define S_ 3
#define G_ 8
#define B_ 2048
#define C_ 512
#define P_ 64
#define N_ (S_ * G_ * B_)   // 49152

typedef __attribute__((ext_vector_type(8))) short short8;
typedef __attribute__((ext_vector_type(4))) float f32x4;
typedef __attribute__((ext_vector_type(4))) unsigned int uint4v;
typedef __attribute__((ext_vector_type(2))) unsigned int uint2v;

__device__ __forceinline__ unsigned f2bf1(float f) {
    union { float f; unsigned u; } c; c.f = f;
    unsigned u = c.u;
    u += 0x7fffu + ((u >> 16) & 1u);   // RNE
    return u >> 16;
}
__device__ __forceinline__ unsigned pk2(float a, float b) {
    return f2bf1(a) | (f2bf1(b) << 16);
}

// ---------------------------------------------------------------------------
// Kernel 0: zero the outputs accumulator region
// ---------------------------------------------------------------------------
__global__ void zero_kernel(float* __restrict__ out) {
    int i = blockIdx.x * blockDim.x + threadIdx.x;   // 65536 float4 slots
    ((f32x4*)out)[i] = (f32x4){0.f, 0.f, 0.f, 0.f};
}

// ---------------------------------------------------------------------------
// Kernel 1: prep — w -> bf16 row-major, csq[p], rbeta[p] = 1/sigmoid(sf)
// ---------------------------------------------------------------------------
__global__ __launch_bounds__(64) void prep_kernel(
    const float* __restrict__ w, const float* __restrict__ sf,
    unsigned short* __restrict__ wb, float* __restrict__ csq,
    float* __restrict__ rbeta)
{
    const int p = blockIdx.x, l = threadIdx.x;
    const float* wr = w + (size_t)p * C_ + l * 8;
    f32x4 a = *(const f32x4*)wr;
    f32x4 b = *(const f32x4*)(wr + 4);
    float s = a[0]*a[0] + a[1]*a[1] + a[2]*a[2] + a[3]*a[3]
            + b[0]*b[0] + b[1]*b[1] + b[2]*b[2] + b[3]*b[3];
    uint4v pk;
    pk.x = pk2(a[0], a[1]); pk.y = pk2(a[2], a[3]);
    pk.z = pk2(b[0], b[1]); pk.w = pk2(b[2], b[3]);
    *(uint4v*)&wb[(size_t)p * C_ + l * 8] = pk;
#pragma unroll
    for (int off = 1; off < 64; off <<= 1) s += __shfl_xor(s, off, 64);
    if (l == 0) csq[p] = s;
    if (p == 0) rbeta[l] = 1.0f + expf(-sf[l]);
}

#define XSTR 72   // bf16 LDS stride for b128-frag tiles (rows 144 B: 2-way banks)
#define NSTR 66   // bf16 LDS stride for u16-gather tile (2-way banks)

// ---------------------------------------------------------------------------
// Kernel 2: assign GEMM. 768 blocks (64 rows) x 256 thr, BK=64, 8 chunks.
// Register-prefetch pipeline: ds_write(cur) -> global load(next) -> barrier
// -> MFMA, so next chunk's HBM loads fly during compute. x staged bf16
// (xsq fused in registers at load). Softmax by shuffles. Epilogue: assign
// fp32 + LDS-transposed bf16 a_t[p][n] (lg aliases the staging LDS).
// ---------------------------------------------------------------------------
__global__ __launch_bounds__(256, 3) void assign_v5(
    const float* __restrict__ x, const unsigned short* __restrict__ wb,
    const float* __restrict__ csq, const float* __restrict__ rbeta,
    float* __restrict__ assign, unsigned short* __restrict__ a_t)
{
    __shared__ __align__(16) char smem[64 * XSTR * 2 * 2];   // 18432 B
    unsigned short* xs  = (unsigned short*)smem;              // [64][72]
    unsigned short* wsh = (unsigned short*)(smem + 64 * XSTR * 2);
    float* lg = (float*)smem;                                 // alias [64][68]
    __shared__ float xsq_s[64];

    const int t = threadIdx.x, lane = t & 63, wv = t >> 6;
    const int q = lane >> 4, col = lane & 15;
    const int n0 = blockIdx.x * 64;
    const int srow = t >> 4, sseg = t & 15;   // x staging: row srow+16i, 16 f32
    const int wp = t >> 3, wseg = t & 7;      // w staging

    float csqv[4], rbv[4];
#pragma unroll
    for (int nt = 0; nt < 4; ++nt) {
        csqv[nt] = csq[16 * nt + col];
        rbv[nt]  = rbeta[16 * nt + col];
    }

    f32x4 acc[4];
#pragma unroll
    for (int nt = 0; nt < 4; ++nt) acc[nt] = (f32x4){0.f, 0.f, 0.f, 0.f};
    float xacc[4] = {0.f, 0.f, 0.f, 0.f};

    f32x4 xr[2][4]; uint4v wr[2][2];
#pragma unroll
    for (int i = 0; i < 4; ++i)
        xr[0][i] = *(const f32x4*)(x + (size_t)(n0 + srow + 16 * i) * C_ + sseg * 4);
#pragma unroll
    for (int i = 0; i < 2; ++i)
        wr[0][i] = *(const uint4v*)&wb[(size_t)(wp + 32 * i) * C_ + wseg * 8];

#pragma unroll
    for (int ch = 0; ch < 8; ++ch) {
        const int cur = ch & 1, nxt = cur ^ 1;
        if (ch) __syncthreads();
        // ---- write current chunk to LDS (fuse |x|^2 partials) ----
#pragma unroll
        for (int i = 0; i < 4; ++i) {
            f32x4 v = xr[cur][i];
            xacc[i] += v.x*v.x + v.y*v.y + v.z*v.z + v.w*v.w;
            uint2v u; u.x = pk2(v.x, v.y); u.y = pk2(v.z, v.w);
            *(uint2v*)&xs[(srow + 16 * i) * XSTR + sseg * 4] = u;
        }
#pragma unroll
        for (int i = 0; i < 2; ++i)
            *(uint4v*)&wsh[(wp + 32 * i) * XSTR + wseg * 8] = wr[cur][i];
        // ---- issue next chunk's global loads (in flight across MFMA) ----
        if (ch < 7) {
            const int k0 = (ch + 1) * 64;
#pragma unroll
            for (int i = 0; i < 4; ++i)
                xr[nxt][i] = *(const f32x4*)(x + (size_t)(n0 + srow + 16 * i) * C_ + k0 + sseg * 4);
#pragma unroll
            for (int i = 0; i < 2; ++i)
                wr[nxt][i] = *(const uint4v*)&wb[(size_t)(wp + 32 * i) * C_ + k0 + wseg * 8];
        }
        __syncthreads();
        // ---- MFMA phase ----
#pragma unroll
        for (int s = 0; s < 2; ++s) {
            const int koff = s * 32 + q * 8;
            short8 af = *(const short8*)&xs[(16 * wv + col) * XSTR + koff];
#pragma unroll
            for (int nt = 0; nt < 4; ++nt) {
                short8 bf = *(const short8*)&wsh[(16 * nt + col) * XSTR + koff];
                acc[nt] = __builtin_amdgcn_mfma_f32_16x16x32_bf16(af, bf, acc[nt], 0, 0, 0);
            }
        }
    }

    // ---- |x|^2: reduce 16-lane staging groups, publish via LDS ----
#pragma unroll
    for (int i = 0; i < 4; ++i) {
#pragma unroll
        for (int off = 1; off < 16; off <<= 1)
            xacc[i] += __shfl_xor(xacc[i], off, 64);
    }
    if ((lane & 15) == 0) {
#pragma unroll
        for (int i = 0; i < 4; ++i) xsq_s[srow + 16 * i] = xacc[i];
    }
    __syncthreads();

    // ---- logits + softmax (shuffle over 16-lane groups) ----
    float vals[4][4];
#pragma unroll
    for (int reg = 0; reg < 4; ++reg) {
        const int row = 16 * wv + 4 * q + reg;
        const float xq = xsq_s[row];
        float vmax = -3.4e38f;
#pragma unroll
        for (int nt = 0; nt < 4; ++nt) {
            float v = 2.0f * acc[nt][reg] - xq - csqv[nt];
            v = fminf(v, 0.0f) * rbv[nt];
            vals[reg][nt] = v;
            vmax = fmaxf(vmax, v);
        }
#pragma unroll
        for (int off = 1; off < 16; off <<= 1)
            vmax = fmaxf(vmax, __shfl_xor(vmax, off, 64));
        float ss = 0.f;
#pragma unroll
        for (int nt = 0; nt < 4; ++nt) { vals[reg][nt] = __expf(vals[reg][nt] - vmax); ss += vals[reg][nt]; }
#pragma unroll
        for (int off = 1; off < 16; off <<= 1)
            ss += __shfl_xor(ss, off, 64);
        const float inv = 1.0f / ss;
#pragma unroll
        for (int nt = 0; nt < 4; ++nt) vals[reg][nt] *= inv;
    }
    __syncthreads();   // all waves past LDS reads -> lg may alias xs/wsh

    // ---- store assign fp32 + scratch for transpose ----
#pragma unroll
    for (int reg = 0; reg < 4; ++reg) {
        const int row = 16 * wv + 4 * q + reg;
#pragma unroll
        for (int nt = 0; nt < 4; ++nt) {
            lg[row * 68 + 16 * nt + col] = vals[reg][nt];
            assign[(size_t)(n0 + row) * P_ + 16 * nt + col] = vals[reg][nt];
        }
    }
    __syncthreads();

    // ---- transposed bf16 a_t[p][n]: thread (p=lane, n-quarter=wv) ----
    const int p = lane;
    float v[16];
#pragma unroll
    for (int i = 0; i < 16; ++i) v[i] = lg[(wv * 16 + i) * 68 + p];
    uint4v d0, d1;
    d0.x = pk2(v[0], v[1]);   d0.y = pk2(v[2], v[3]);
    d0.z = pk2(v[4], v[5]);   d0.w = pk2(v[6], v[7]);
    d1.x = pk2(v[8], v[9]);   d1.y = pk2(v[10], v[11]);
    d1.z = pk2(v[12], v[13]); d1.w = pk2(v[14], v[15]);
    unsigned short* dst = a_t + (size_t)p * N_ + n0 + wv * 16;
    *(uint4v*)dst = d0;
    *(uint4v*)(dst + 8) = d1;
}

// ---------------------------------------------------------------------------
// Kernel 3: group GEMM out[g,p,c] += sum_n a[n,p] x[n,c]. Grid (8,8,12),
// 64p x 64c x BK=64, same register-prefetch pipeline. A-frags b128 from
// ash[p][n] (stride 72, 2-way); x kept n-major in LDS (stride 66) and
// B-frags gathered with 8x ds_read_u16 (bank map = const+8q+col/2: 2-way,
// free) — avoids the provably-conflicted transposed-store layout.
// ---------------------------------------------------------------------------
__global__ __launch_bounds__(256, 3) void group_v5(
    const float* __restrict__ x, const unsigned short* __restrict__ a_t,
    float* __restrict__ out)
{
    __shared__ __align__(16) unsigned short ash[64 * XSTR];  // [p][n]
    __shared__ __align__(16) unsigned short xsn[64 * NSTR];  // [n][c]

    const int t = threadIdx.x, lane = t & 63, wv = t >> 6;
    const int q = lane >> 4, col = lane & 15;
    const int g = blockIdx.x, c0 = blockIdx.y * 64, ks = blockIdx.z;
    const int sc = ks >> 2, b0 = (ks & 3) * 512;
    const size_t base = (size_t)sc * (G_ * B_) + (size_t)g * B_ + b0;
    const int ap = t >> 3, aseg = t & 7;      // a staging
    const int srow = t >> 4, sseg = t & 15;   // x staging (n-major, as assign)

    f32x4 acc[4];
#pragma unroll
    for (int mt = 0; mt < 4; ++mt) acc[mt] = (f32x4){0.f, 0.f, 0.f, 0.f};

    uint4v ar[2][2]; f32x4 xr[2][4];
#pragma unroll
    for (int i = 0; i < 2; ++i)
        ar[0][i] = *(const uint4v*)&a_t[(size_t)(ap + 32 * i) * N_ + base + aseg * 8];
#pragma unroll
    for (int i = 0; i < 4; ++i)
        xr[0][i] = *(const f32x4*)(x + (base + srow + 16 * i) * C_ + c0 + sseg * 4);

#pragma unroll
    for (int ch = 0; ch < 8; ++ch) {
        const int cur = ch & 1, nxt = cur ^ 1;
        if (ch) __syncthreads();
#pragma unroll
        for (int i = 0; i < 2; ++i)
            *(uint4v*)&ash[(ap + 32 * i) * XSTR + aseg * 8] = ar[cur][i];
#pragma unroll
        for (int i = 0; i < 4; ++i) {
            f32x4 v = xr[cur][i];
            uint2v u; u.x = pk2(v.x, v.y); u.y = pk2(v.z, v.w);
            *(uint2v*)&xsn[(srow + 16 * i) * NSTR + sseg * 4] = u;
        }
        if (ch < 7) {
            const int nb = (ch + 1) * 64;
#pragma unroll
            for (int i = 0; i < 2; ++i)
                ar[nxt][i] = *(const uint4v*)&a_t[(size_t)(ap + 32 * i) * N_ + base + nb + aseg * 8];
#pragma unroll
            for (int i = 0; i < 4; ++i)
                xr[nxt][i] = *(const f32x4*)(x + (base + nb + srow + 16 * i) * C_ + c0 + sseg * 4);
        }
        __syncthreads();
#pragma unroll
        for (int s = 0; s < 2; ++s) {
            const int koff = s * 32 + q * 8;
            short8 bfr;
#pragma unroll
            for (int j = 0; j < 8; ++j)
                bfr[j] = xsn[(koff + j) * NSTR + 16 * wv + col];
#pragma unroll
            for (int mt = 0; mt < 4; ++mt) {
                short8 afr = *(const short8*)&ash[(16 * mt + col) * XSTR + koff];
                acc[mt] = __builtin_amdgcn_mfma_f32_16x16x32_bf16(afr, bfr, acc[mt], 0, 0, 0);
            }
        }
    }

    // ---- epilogue: p = 16*mt + 4q + reg, c = c0 + 16*wv + col ----
#pragma unroll
    for (int mt = 0; mt < 4; ++mt) {
#pragma unroll
        for (int reg = 0; reg < 4; ++reg) {
            const int p = 16 * mt + 4 * q + reg;
            const int c = c0 + 16 * wv + col;
            atomicAdd(&out[(size_t)g * (P_ * C_) + (size_t)p * C_ + c], acc[mt][reg]);
        }
    }
}

// ---------------------------------------------------------------------------
extern "C" void kernel_launch(void* const* d_in, const int* in_sizes, int n_in,
                              void* d_out, int out_size, void* d_ws, size_t ws_size,
                              hipStream_t stream) {
    const float* x  = (const float*)d_in[0];   // node_feats [3, 16384, 512]
    const float* w  = (const float*)d_in[1];   // weight [64, 512]
    const float* sf = (const float*)d_in[2];   // smooth_factor [64]

    float* out    = (float*)d_out;              // outputs [8, 64, 512]
    float* assign = out + (size_t)G_ * P_ * C_; // assign [N, 64] fp32

    unsigned short* wb    = (unsigned short*)d_ws;                  // 65536 B
    float*          csq   = (float*)((char*)d_ws + 65536);          // 256 B
    float*          rbeta = (float*)((char*)d_ws + 65792);          // 256 B
    unsigned short* a_t   = (unsigned short*)((char*)d_ws + 66048); // 6.3 MB

    zero_kernel<<<(G_ * P_ * C_) / (4 * 256), 256, 0, stream>>>(out);
    prep_kernel<<<P_, 64, 0, stream>>>(w, sf, wb, csq, rbeta);
    assign_v5<<<N_ / 64, 256, 0, stream>>>(x, wb, csq, rbeta, assign, a_t);
    dim3 gridB(G_, C_ / 64, 12);
    group_v5<<<gridB, 256, 0, stream>>>(x, a_t, out);
}

// Round 6
// 185.273 us; speedup vs baseline: 1.1224x; 1.0186x over previous
//
#include <hip/hip_runtime.h>
#include <math.h>

#define S_ 3
#define G_ 8
#define B_ 2048
#define C_ 512
#define P_ 64
#define N_ (S_ * G_ * B_)   // 49152

typedef __attribute__((ext_vector_type(8))) short short8;
typedef __attribute__((ext_vector_type(4))) float f32x4;
typedef __attribute__((ext_vector_type(4))) unsigned int uint4v;

__device__ __forceinline__ unsigned f2bf1(float f) {
    union { float f; unsigned u; } c; c.f = f;
    unsigned u = c.u;
    u += 0x7fffu + ((u >> 16) & 1u);   // RNE
    return u >> 16;
}
__device__ __forceinline__ unsigned pk2(float a, float b) {
    return f2bf1(a) | (f2bf1(b) << 16);
}
// async global->LDS, 16B/lane; LDS dest = wave-uniform base + lane*16
__device__ __forceinline__ void gl_lds16(const void* g, void* l) {
    __builtin_amdgcn_global_load_lds(
        (const __attribute__((address_space(1))) void*)g,
        (__attribute__((address_space(3))) void*)l, 16, 0, 0);
}

// ---------------------------------------------------------------------------
// prep: w -> bf16 row-major, csq[p], rbeta[p] = 1/sigmoid(sf)
// ---------------------------------------------------------------------------
__global__ __launch_bounds__(64) void prep_kernel(
    const float* __restrict__ w, const float* __restrict__ sf,
    unsigned short* __restrict__ wb, float* __restrict__ csq,
    float* __restrict__ rbeta)
{
    const int p = blockIdx.x, l = threadIdx.x;
    const float* wr = w + (size_t)p * C_ + l * 8;
    f32x4 a = *(const f32x4*)wr;
    f32x4 b = *(const f32x4*)(wr + 4);
    float s = a[0]*a[0] + a[1]*a[1] + a[2]*a[2] + a[3]*a[3]
            + b[0]*b[0] + b[1]*b[1] + b[2]*b[2] + b[3]*b[3];
    uint4v pk;
    pk.x = pk2(a[0], a[1]); pk.y = pk2(a[2], a[3]);
    pk.z = pk2(b[0], b[1]); pk.w = pk2(b[2], b[3]);
    *(uint4v*)&wb[(size_t)p * C_ + l * 8] = pk;
#pragma unroll
    for (int off = 1; off < 64; off <<= 1) s += __shfl_xor(s, off, 64);
    if (l == 0) csq[p] = s;
    if (p == 0) rbeta[l] = 1.0f + expf(-sf[l]);
}

// ---------------------------------------------------------------------------
// assign_v6: 768 blocks x 256 thr, 64 rows, BK=64, gl_lds double-buffer.
// x: no-pad fp32 [64][64] per buf, global-side granule swizzle
//   p(row) = ((row>>1)&7)|(row&8)  -> A-frag b128 reads exactly 2-way banks.
// w: register-prefetch + ds_write, bf16 stride 72 (2-way, conflict-free).
// Loop: ds_write(w cur); barrier(drains gl_lds cur, issued 1 compute ago);
//       issue w loads + gl_lds for next; MFMA on cur.
// ---------------------------------------------------------------------------
__global__ __launch_bounds__(256, 3) void assign_v6(
    const float* __restrict__ x, const unsigned short* __restrict__ wb,
    const float* __restrict__ csq, const float* __restrict__ rbeta,
    float* __restrict__ assign, unsigned short* __restrict__ a_t)
{
    __shared__ __align__(16) float xsb[2][64 * 64];          // 32 KB
    __shared__ __align__(16) unsigned short wsb[2][64 * 72]; // 18 KB
    __shared__ float xsq_s[64];
    float* lg = &xsb[0][0];   // epilogue alias [64][68] fp32 (17.4 KB)

    const int t = threadIdx.x, lane = t & 63, wv = t >> 6;
    const int q = lane >> 4, col = lane & 15;
    const int n0 = blockIdx.x * 64;
    const int ro = lane >> 4, sslot = lane & 15;   // x staging
    const int wp = t >> 3, wseg = t & 7;           // w staging

    // lane-const global staging pointers (row + swizzled granule)
    const float* gx[4];
#pragma unroll
    for (int i = 0; i < 4; ++i) {
        const int row = 16 * wv + 4 * i + ro;
        const int pr  = ((row >> 1) & 7) | (row & 8);
        gx[i] = x + (size_t)(n0 + row) * C_ + ((sslot ^ pr) << 2);
    }
    const int prA = ((col >> 1) & 7) | (col & 8);  // p(16*wv+col)

    float csqv[4], rbv[4];
#pragma unroll
    for (int nt = 0; nt < 4; ++nt) {
        csqv[nt] = csq[16 * nt + col];
        rbv[nt]  = rbeta[16 * nt + col];
    }

    f32x4 acc[4];
#pragma unroll
    for (int nt = 0; nt < 4; ++nt) acc[nt] = (f32x4){0.f, 0.f, 0.f, 0.f};
    float xsq = 0.f;

    // prologue: chunk 0 in flight
    uint4v wr0 = *(const uint4v*)&wb[(size_t)wp * C_ + wseg * 8];
    uint4v wr1 = *(const uint4v*)&wb[(size_t)(wp + 32) * C_ + wseg * 8];
#pragma unroll
    for (int i = 0; i < 4; ++i) gl_lds16(gx[i], &xsb[0][(16 * wv + 4 * i) * 64]);

#pragma unroll
    for (int ch = 0; ch < 8; ++ch) {
        const int cur = ch & 1;
        *(uint4v*)&wsb[cur][wp * 72 + wseg * 8]        = wr0;
        *(uint4v*)&wsb[cur][(wp + 32) * 72 + wseg * 8] = wr1;
        __syncthreads();
        if (ch < 7) {
            const int k0 = (ch + 1) * 64;
            wr0 = *(const uint4v*)&wb[(size_t)wp * C_ + k0 + wseg * 8];
            wr1 = *(const uint4v*)&wb[(size_t)(wp + 32) * C_ + k0 + wseg * 8];
#pragma unroll
            for (int i = 0; i < 4; ++i)
                gl_lds16(gx[i] + k0, &xsb[cur ^ 1][(16 * wv + 4 * i) * 64]);
        }
#pragma unroll
        for (int s = 0; s < 2; ++s) {
            const int g0 = 8 * s + 2 * q;
            f32x4 f0 = *(const f32x4*)&xsb[cur][(16 * wv + col) * 64 + ((g0 ^ prA) << 2)];
            f32x4 f1 = *(const f32x4*)&xsb[cur][(16 * wv + col) * 64 + (((g0 + 1) ^ prA) << 2)];
            xsq += f0.x*f0.x + f0.y*f0.y + f0.z*f0.z + f0.w*f0.w
                 + f1.x*f1.x + f1.y*f1.y + f1.z*f1.z + f1.w*f1.w;
            union { uint4v u; short8 s8; } cv;
            cv.u.x = pk2(f0.x, f0.y); cv.u.y = pk2(f0.z, f0.w);
            cv.u.z = pk2(f1.x, f1.y); cv.u.w = pk2(f1.z, f1.w);
            const int koff = s * 32 + q * 8;
#pragma unroll
            for (int nt = 0; nt < 4; ++nt) {
                short8 bf = *(const short8*)&wsb[cur][(16 * nt + col) * 72 + koff];
                acc[nt] = __builtin_amdgcn_mfma_f32_16x16x32_bf16(cv.s8, bf, acc[nt], 0, 0, 0);
            }
        }
    }

    // |x|^2: lane holds its q-quarter of row 16wv+col -> reduce over q
    xsq += __shfl_xor(xsq, 16, 64);
    xsq += __shfl_xor(xsq, 32, 64);
    if (q == 0) xsq_s[16 * wv + col] = xsq;
    __syncthreads();

    // logits + softmax (shuffle over 16-lane groups)
    float vals[4][4];
#pragma unroll
    for (int reg = 0; reg < 4; ++reg) {
        const int row = 16 * wv + 4 * q + reg;
        const float xq = xsq_s[row];
        float vmax = -3.4e38f;
#pragma unroll
        for (int nt = 0; nt < 4; ++nt) {
            float v = 2.0f * acc[nt][reg] - xq - csqv[nt];
            v = fminf(v, 0.0f) * rbv[nt];
            vals[reg][nt] = v;
            vmax = fmaxf(vmax, v);
        }
#pragma unroll
        for (int off = 1; off < 16; off <<= 1)
            vmax = fmaxf(vmax, __shfl_xor(vmax, off, 64));
        float ss = 0.f;
#pragma unroll
        for (int nt = 0; nt < 4; ++nt) { vals[reg][nt] = __expf(vals[reg][nt] - vmax); ss += vals[reg][nt]; }
#pragma unroll
        for (int off = 1; off < 16; off <<= 1)
            ss += __shfl_xor(ss, off, 64);
        const float inv = 1.0f / ss;
#pragma unroll
        for (int nt = 0; nt < 4; ++nt) vals[reg][nt] *= inv;
    }

    // store assign fp32 + lg scratch for transpose (lg aliases xsb[0], dead)
#pragma unroll
    for (int reg = 0; reg < 4; ++reg) {
        const int row = 16 * wv + 4 * q + reg;
#pragma unroll
        for (int nt = 0; nt < 4; ++nt) {
            lg[row * 68 + 16 * nt + col] = vals[reg][nt];
            assign[(size_t)(n0 + row) * P_ + 16 * nt + col] = vals[reg][nt];
        }
    }
    __syncthreads();

    // transposed bf16 a_t[p][n]: thread (p = lane, n-quarter = wv)
    const int p = lane;
    float v[16];
#pragma unroll
    for (int i = 0; i < 16; ++i) v[i] = lg[(wv * 16 + i) * 68 + p];
    uint4v d0, d1;
    d0.x = pk2(v[0], v[1]);   d0.y = pk2(v[2], v[3]);
    d0.z = pk2(v[4], v[5]);   d0.w = pk2(v[6], v[7]);
    d1.x = pk2(v[8], v[9]);   d1.y = pk2(v[10], v[11]);
    d1.z = pk2(v[12], v[13]); d1.w = pk2(v[14], v[15]);
    unsigned short* dst = a_t + (size_t)p * N_ + n0 + wv * 16;
    *(uint4v*)dst = d0;
    *(uint4v*)(dst + 8) = d1;
}

// ---------------------------------------------------------------------------
// group_v6: out-partials[g,ct,ks][p][c] = sum_n a[n,p] x[n,c]. Grid (8,8,12).
// Both streams via gl_lds double-buffer (single barrier per chunk):
//  a_t: no-pad [p][64n] bf16 (A-frags b128, 4-way accepted);
//  x:   no-pad fp32 [n][64c] with granule swizzle perm(n)=((n>>3)&3)|(((n>>3)&1)<<2)
//       -> per-lane b32 gathers land exactly 2-way. No atomics: plain stores
//       to per-block partial tiles, reduced by reduce_out.
// ---------------------------------------------------------------------------
__global__ __launch_bounds__(256, 3) void group_v6(
    const float* __restrict__ x, const unsigned short* __restrict__ a_t,
    float* __restrict__ part)
{
    __shared__ __align__(16) float xsb[2][64 * 64];           // 32 KB
    __shared__ __align__(16) unsigned short asb[2][64 * 64];  // 16 KB

    const int t = threadIdx.x, lane = t & 63, wv = t >> 6;
    const int q = lane >> 4, col = lane & 15;
    const int g = blockIdx.x, ct = blockIdx.y, ks = blockIdx.z;
    const int c0 = ct * 64, sc = ks >> 2, b0 = (ks & 3) * 512;
    const size_t base = (size_t)sc * (G_ * B_) + (size_t)g * B_ + b0;
    const int ro = lane >> 4, sslot = lane & 15;   // x staging
    const int aro = lane >> 3, aseg = lane & 7;    // a staging

    const float* gx[4];
#pragma unroll
    for (int i = 0; i < 4; ++i) {
        const int n  = 16 * wv + 4 * i + ro;
        const int pm = ((n >> 3) & 3) | (((n >> 3) & 1) << 2);
        gx[i] = x + (base + n) * C_ + c0 + ((sslot ^ pm) << 2);
    }
    const unsigned short* ga[2];
#pragma unroll
    for (int i = 0; i < 2; ++i) {
        const int p = 16 * wv + 8 * i + aro;
        ga[i] = a_t + (size_t)p * N_ + base + aseg * 8;
    }
    const int cl = 16 * wv + col;
    const int permq = q | ((q & 1) << 2);
    const int cswz  = (((cl >> 2) ^ permq) << 2) | (cl & 3);

    f32x4 acc[4];
#pragma unroll
    for (int mt = 0; mt < 4; ++mt) acc[mt] = (f32x4){0.f, 0.f, 0.f, 0.f};

    // prologue
#pragma unroll
    for (int i = 0; i < 4; ++i) gl_lds16(gx[i], &xsb[0][(16 * wv + 4 * i) * 64]);
#pragma unroll
    for (int i = 0; i < 2; ++i) gl_lds16(ga[i], &asb[0][(16 * wv + 8 * i) * 64]);

#pragma unroll
    for (int ch = 0; ch < 8; ++ch) {
        const int cur = ch & 1;
        __syncthreads();
        if (ch < 7) {
            const int nb = (ch + 1) * 64;
#pragma unroll
            for (int i = 0; i < 4; ++i)
                gl_lds16(gx[i] + (size_t)nb * C_, &xsb[cur ^ 1][(16 * wv + 4 * i) * 64]);
#pragma unroll
            for (int i = 0; i < 2; ++i)
                gl_lds16(ga[i] + nb, &asb[cur ^ 1][(16 * wv + 8 * i) * 64]);
        }
#pragma unroll
        for (int s = 0; s < 2; ++s) {
            const int koff = s * 32 + q * 8;
            float gv[8];
#pragma unroll
            for (int j = 0; j < 8; ++j) gv[j] = xsb[cur][(koff + j) * 64 + cswz];
            union { uint4v u; short8 s8; } cv;
            cv.u.x = pk2(gv[0], gv[1]); cv.u.y = pk2(gv[2], gv[3]);
            cv.u.z = pk2(gv[4], gv[5]); cv.u.w = pk2(gv[6], gv[7]);
#pragma unroll
            for (int mt = 0; mt < 4; ++mt) {
                short8 af = *(const short8*)&asb[cur][(16 * mt + col) * 64 + koff];
                acc[mt] = __builtin_amdgcn_mfma_f32_16x16x32_bf16(af, cv.s8, acc[mt], 0, 0, 0);
            }
        }
    }

    // plain stores of the 64p x 64c partial tile
    float* pt = part + (((size_t)(g * 8 + ct) * 12) + ks) * 4096;
#pragma unroll
    for (int mt = 0; mt < 4; ++mt)
#pragma unroll
        for (int reg = 0; reg < 4; ++reg) {
            const int p = 16 * mt + 4 * q + reg;
            pt[p * 64 + cl] = acc[mt][reg];
        }
}

// ---------------------------------------------------------------------------
// reduce_out: out[g,p,c] = sum_{ks=0..11} part[g,ct,ks][p][cl]
// ---------------------------------------------------------------------------
__global__ __launch_bounds__(256) void reduce_out(
    const float* __restrict__ part, float* __restrict__ out)
{
    const int idx = blockIdx.x * 256 + threadIdx.x;   // 262144 total
    const int g = idx >> 15, r = idx & 32767;
    const int p = r >> 9,  c = r & 511;
    const int ct = c >> 6, cl = c & 63;
    const float* src = part + (((size_t)(g * 8 + ct) * 12)) * 4096 + p * 64 + cl;
    float s = 0.f;
#pragma unroll
    for (int ks = 0; ks < 12; ++ks) s += src[(size_t)ks * 4096];
    out[idx] = s;
}

// ---------------------------------------------------------------------------
extern "C" void kernel_launch(void* const* d_in, const int* in_sizes, int n_in,
                              void* d_out, int out_size, void* d_ws, size_t ws_size,
                              hipStream_t stream) {
    const float* x  = (const float*)d_in[0];   // node_feats [3, 16384, 512]
    const float* w  = (const float*)d_in[1];   // weight [64, 512]
    const float* sf = (const float*)d_in[2];   // smooth_factor [64]

    float* out    = (float*)d_out;              // outputs [8, 64, 512]
    float* assign = out + (size_t)G_ * P_ * C_; // assign [N, 64] fp32

    unsigned short* wb    = (unsigned short*)d_ws;                   // 64 KB
    float*          csq   = (float*)((char*)d_ws + 65536);           // 256 B
    float*          rbeta = (float*)((char*)d_ws + 65792);           // 256 B
    unsigned short* a_t   = (unsigned short*)((char*)d_ws + 66048);  // 6.29 MB
    float*          part  = (float*)((char*)d_ws + 6553600);         // 12.6 MB

    prep_kernel<<<P_, 64, 0, stream>>>(w, sf, wb, csq, rbeta);
    assign_v6<<<N_ / 64, 256, 0, stream>>>(x, wb, csq, rbeta, assign, a_t);
    dim3 gridB(G_, C_ / 64, 12);
    group_v6<<<gridB, 256, 0, stream>>>(x, a_t, part);
    reduce_out<<<(G_ * P_ * C_) / 256, 256, 0, stream>>>(part, out);
}